// Round 5
// baseline (469.522 us; speedup 1.0000x reference)
//
#include <hip/hip_runtime.h>
#include <hip/hip_bf16.h>

// Conv2d 3x3 s1 p1, NCHW fp32: N=32, Cin=256, H=W=56, Cout=256.
// R5 (= R4 resubmit + halo_zero granule fix): bf16 hi/lo split,
// MFMA 32x32x16, T3-min schedule (sW double-buffered, 1 barrier/tap),
// T2 XOR slot-swizzle on sW/sX, halo-zero kernel instead of 220MB memset.

#define NB   32
#define CIN  256
#define HH   56
#define WW   56
#define COUT 256

typedef unsigned short u16;
typedef __attribute__((ext_vector_type(8)))  short bf16x8;
typedef __attribute__((ext_vector_type(16))) float f32x16;

#define XS_ELEMS (32u*58u*58u*256u)
#define XS_BYTES ((size_t)XS_ELEMS*2u)
#define WP_ELEMS (256u*2304u)
#define WP_BYTES ((size_t)WP_ELEMS*2u)
#define WS_NEED  (2u*XS_BYTES + 2u*WP_BYTES)

__device__ __forceinline__ void gld16(const u16* g, u16* l) {
    __builtin_amdgcn_global_load_lds(
        (const __attribute__((address_space(1))) void*)g,
        (__attribute__((address_space(3))) void*)l, 16, 0, 0);
}

__device__ __forceinline__ u16 bf16_hi_bits(float v, float* hv) {
    __hip_bfloat16 hb = __float2bfloat16(v);
    *hv = __bfloat162float(hb);
    return *reinterpret_cast<u16*>(&hb);
}

// ---- pre-pass 0: zero only the halo border cells of xs_hi/xs_lo ----
// 228 border cells per image, 256 u16 per cell = 32 granules of 8 u16 (16B).
__global__ __launch_bounds__(256) void halo_zero(u16* __restrict__ xh,
                                                 u16* __restrict__ xl) {
    unsigned i = blockIdx.x*256u + threadIdx.x;   // img*228*32 + cell*32 + g
    if (i >= 32u*228u*32u) return;
    unsigned g    = i & 31u;
    unsigned cell = (i >> 5) % 228u;
    unsigned img  = i / (228u*32u);
    unsigned h, w;
    if      (cell < 58)  { h = 0;                w = cell; }
    else if (cell < 116) { h = 57;               w = cell - 58; }
    else if (cell < 172) { h = 1 + (cell - 116); w = 0; }
    else                 { h = 1 + (cell - 172); w = 57; }
    unsigned o = ((img*58u + h)*58u + w)*256u + g*8u;
    uint4 z = {0u,0u,0u,0u};
    *reinterpret_cast<uint4*>(&xh[o]) = z;
    *reinterpret_cast<uint4*>(&xl[o]) = z;
}

// ---- pre-pass 1: x (NCHW f32) -> xs_hi/xs_lo (padded NHWC bf16) ----
__global__ __launch_bounds__(256) void xsplit(const float* __restrict__ x,
                                              u16* __restrict__ xh,
                                              u16* __restrict__ xl) {
    __shared__ float tile[32][57];
    const int t  = threadIdx.x;
    const int b  = blockIdx.x;              // n*(8*56) + cg*56 + h
    const int n  = b / (8*56);
    const int cg = (b / 56) % 8;
    const int h  = b % 56;
    const float* src = x + ((size_t)n*CIN + cg*32) * 3136 + (unsigned)h*56;
    #pragma unroll
    for (int k = 0; k < 7; ++k) {           // 32*56 = 1792 = 7*256
        int idx = t + k*256;
        int c = idx / 56, w = idx % 56;
        tile[c][w] = src[(unsigned)c*3136 + w];
    }
    __syncthreads();
    const unsigned obase = (((unsigned)n*58 + h + 1)*58 + 1)*256 + cg*32;
    #pragma unroll
    for (int k = 0; k < 7; ++k) {
        int idx = t + k*256;
        int w = idx / 32, c = idx % 32;
        float v = tile[c][w];
        float hv;
        u16 hbits = bf16_hi_bits(v, &hv);
        float r;
        u16 lbits = bf16_hi_bits(v - hv, &r);
        unsigned o = obase + (unsigned)w*256 + c;
        xh[o] = hbits;
        xl[o] = lbits;
    }
}

// ---- pre-pass 2: w (OIHW f32) -> wp_hi/wp_lo [co][tap][ci] bf16 ----
__global__ __launch_bounds__(256) void wsplit(const float* __restrict__ w,
                                              u16* __restrict__ wh,
                                              u16* __restrict__ wl) {
    unsigned i = blockIdx.x*256u + threadIdx.x;
    if (i >= WP_ELEMS) return;
    unsigned co  = i / 2304u;
    unsigned r   = i % 2304u;
    unsigned tap = r >> 8;
    unsigned ci  = r & 255u;
    float v = w[(size_t)co*2304u + ci*9u + tap];
    float hv;
    u16 hbits = bf16_hi_bits(v, &hv);
    float rr;
    u16 lbits = bf16_hi_bits(v - hv, &rr);
    wh[i] = hbits;
    wl[i] = lbits;
}

// ---- main conv kernel ----
// Block: 256 thr / 4 waves; tile 128co x 2img x (8x8 sp). Wave: 64co x 64sp.
// MFMA 32x32x16: A row=lane&31, k=(lane>>5)*8+j ; B col=lane&31, same k.
// C/D: col=lane&31, row=(reg&3)+8*(reg>>2)+4*(lane>>5)  [m74/m101].
// LDS rows (co / cell) stride 64B = 4 x 16B slots; slot stored/read XOR
// ((row>>1)&3) — source-swizzled gld16 + swizzled ds_read (rule #21).
__global__ __launch_bounds__(256, 2) void conv_mfma(
    const u16* __restrict__ xs_hi, const u16* __restrict__ xs_lo,
    const u16* __restrict__ wp_hi, const u16* __restrict__ wp_lo,
    const float* __restrict__ bias, float* __restrict__ y) {
    __shared__ __align__(16) u16 sWh[2][4096], sWl[2][4096];   // [buf][co128][ci32]
    __shared__ __align__(16) u16 sXh[6400],    sXl[6400];      // [2img*100cell][ci32]

    const int t    = threadIdx.x;
    const int lane = t & 63, wid = t >> 6;
    const int wc   = wid >> 1;          // co half (0/1)
    const int iwv  = wid & 1;           // image   (0/1)
    const int s5   = lane & 31;         // 32-wide row/col index
    const int hi   = lane >> 5;         // k-group

    const int bid  = blockIdx.x;        // (co_t*49 + sp)*16 + nt
    const int co_t = bid / (49*16);
    const int rem  = bid % (49*16);
    const int sp   = rem / 16;
    const int nt   = rem % 16;
    const int h0   = (sp / 7) * 8, w0 = (sp % 7) * 8;
    const int co0  = co_t * 128;
    const int n0   = nt * 2;

    f32x16 acc[2][2];
    #pragma unroll
    for (int m = 0; m < 2; ++m)
        #pragma unroll
        for (int j = 0; j < 2; ++j)
            #pragma unroll
            for (int e = 0; e < 16; ++e) acc[m][j][e] = 0.f;

    // ---- staging helpers (lane-linear LDS dest; source pre-swizzled) ----
    auto STAGE_W = [&](int buf, int ck, int tap) {
        #pragma unroll
        for (int k = 0; k < 2; ++k) {
            const int s  = t + k*256;          // 0..511
            const int co = s >> 2, sl = s & 3;
            const int g  = sl ^ ((co >> 1) & 3);
            const unsigned go = (unsigned)(co0+co)*2304u + (unsigned)tap*256u
                              + (unsigned)ck*32u + (unsigned)g*8u;
            gld16(wp_hi + go, &sWh[buf][(unsigned)s*8u]);
            gld16(wp_lo + go, &sWl[buf][(unsigned)s*8u]);
        }
    };
    auto STAGE_X = [&](int ck) {
        #pragma unroll
        for (int k = 0; k < 4; ++k) {
            const int s = t + k*256;           // 0..799
            if (s < 800) {
                const int cell = s >> 2, sl = s & 3;
                const int g    = sl ^ ((cell >> 1) & 3);
                const int im   = cell / 100, r100 = cell % 100;
                const int r    = r100 / 10,  c    = r100 % 10;
                const unsigned go = (((unsigned)(n0+im)*58u + (unsigned)(h0+r))*58u
                                     + (unsigned)(w0+c))*256u
                                    + (unsigned)ck*32u + (unsigned)g*8u;
                gld16(xs_hi + go, &sXh[(unsigned)s*8u]);
                gld16(xs_lo + go, &sXl[(unsigned)s*8u]);
            }
        }
    };

    STAGE_X(0);
    STAGE_W(0, 0, 0);
    __syncthreads();

    for (int p = 0; p < 72; ++p) {
        const int tap = p % 9;
        const int buf = p & 1;
        if (p + 1 < 72) STAGE_W(buf ^ 1, (p+1)/9, (p+1)%9);   // prefetch next tap

        const int kh = tap / 3, kw = tap % 3;
        #pragma unroll
        for (int ks = 0; ks < 2; ++ks) {
            bf16x8 ah[2], al[2], bh[2], bl[2];
            #pragma unroll
            for (int m = 0; m < 2; ++m) {
                const int co = wc*64 + m*32 + s5;
                const int sl = (ks*2 + hi) ^ ((co >> 1) & 3);
                const unsigned ao = (unsigned)co*32u + (unsigned)sl*8u;
                ah[m] = *reinterpret_cast<const bf16x8*>(&sWh[buf][ao]);
                al[m] = *reinterpret_cast<const bf16x8*>(&sWl[buf][ao]);
            }
            #pragma unroll
            for (int j = 0; j < 2; ++j) {
                const int cell = iwv*100 + (j*4 + (s5>>3) + kh)*10 + ((s5&7) + kw);
                const int sl   = (ks*2 + hi) ^ ((cell >> 1) & 3);
                const unsigned bo = (unsigned)cell*32u + (unsigned)sl*8u;
                bh[j] = *reinterpret_cast<const bf16x8*>(&sXh[bo]);
                bl[j] = *reinterpret_cast<const bf16x8*>(&sXl[bo]);
            }
            #pragma unroll
            for (int m = 0; m < 2; ++m)
                #pragma unroll
                for (int j = 0; j < 2; ++j) {
                    acc[m][j] = __builtin_amdgcn_mfma_f32_32x32x16_bf16(ah[m], bh[j], acc[m][j], 0, 0, 0);
                    acc[m][j] = __builtin_amdgcn_mfma_f32_32x32x16_bf16(ah[m], bl[j], acc[m][j], 0, 0, 0);
                    acc[m][j] = __builtin_amdgcn_mfma_f32_32x32x16_bf16(al[m], bh[j], acc[m][j], 0, 0, 0);
                }
        }
        __syncthreads();                       // drains vmcnt(0): prefetch landed
        if (tap == 8 && p < 71) {              // chunk boundary: restage sX
            STAGE_X(p/9 + 1);
            __syncthreads();
        }
    }

    // ---- epilogue: C/D col=lane&31 (spatial), row=(reg&3)+8*(reg>>2)+4*hi (co) ----
    const int n_img = n0 + iwv;
    #pragma unroll
    for (int m = 0; m < 2; ++m) {
        #pragma unroll
        for (int q = 0; q < 4; ++q) {
            const int cob = co0 + wc*64 + m*32 + 8*q + 4*hi;
            const float4 bv = *reinterpret_cast<const float4*>(&bias[cob]);
            const float bvv[4] = {bv.x, bv.y, bv.z, bv.w};
            #pragma unroll
            for (int j = 0; j < 2; ++j) {
                const int pr = j*4 + (s5 >> 3), pc = s5 & 7;
                #pragma unroll
                for (int rr = 0; rr < 4; ++rr) {
                    const int reg = q*4 + rr;
                    const unsigned yo =
                        (((unsigned)(n_img*COUT + cob + rr))*56u + (unsigned)(h0+pr))*56u
                        + (unsigned)(w0+pc);
                    y[yo] = acc[m][j][reg] + bvv[rr];
                }
            }
        }
    }
}

// ---- fp32 fallback if ws_size is insufficient ----
#define BM 128
#define KC 8
__global__ __launch_bounds__(256, 3) void conv3x3_f32(
    const float* __restrict__ x, const float* __restrict__ wgt,
    const float* __restrict__ bias, float* __restrict__ y) {
    __shared__ float sW[KC * 9][BM];
    __shared__ float sX[KC][10][12];
    const int t = threadIdx.x;
    const int tco = t >> 4, tsp = t & 15;
    const int srow = tsp >> 1, scol0 = (tsp & 1) * 4;
    const int bid = blockIdx.x;
    const int co_t = bid / (49 * NB);
    const int rem = bid % (49 * NB);
    const int sp_t = rem / NB, n = rem % NB;
    const int h0 = (sp_t / 7) * 8, w0 = (sp_t % 7) * 8;
    const int co0 = co_t * BM;
    float acc[8][4];
    #pragma unroll
    for (int r = 0; r < 8; ++r)
        #pragma unroll
        for (int j = 0; j < 4; ++j) acc[r][j] = 0.f;
    const int co_l = t >> 1, half = t & 1;
    for (int ci0 = 0; ci0 < CIN; ci0 += KC) {
        __syncthreads();
        {
            const float4* wsrc = reinterpret_cast<const float4*>(
                wgt + (size_t)(co0 + co_l) * (CIN * 9) + ci0 * 9 + half * 36);
            #pragma unroll
            for (int q = 0; q < 9; ++q) {
                float4 v = wsrc[q];
                const int k0 = half * 36 + q * 4;
                sW[k0 + 0][co_l] = v.x; sW[k0 + 1][co_l] = v.y;
                sW[k0 + 2][co_l] = v.z; sW[k0 + 3][co_l] = v.w;
            }
        }
        for (int idx = t; idx < KC * 100; idx += 256) {
            const int c = idx / 100, r = (idx % 100) / 10, cc = idx % 10;
            const int hh = h0 + r - 1, ww = w0 + cc - 1;
            float v = 0.f;
            if (hh >= 0 && hh < HH && ww >= 0 && ww < WW)
                v = x[(((size_t)n * CIN + (ci0 + c)) * HH + hh) * WW + ww];
            sX[c][r][cc] = v;
        }
        __syncthreads();
        for (int c = 0; c < KC; ++c) {
            #pragma unroll
            for (int kh = 0; kh < 3; ++kh) {
                float xw[8];
                *reinterpret_cast<float4*>(&xw[0]) =
                    *reinterpret_cast<const float4*>(&sX[c][srow + kh][scol0]);
                *reinterpret_cast<float4*>(&xw[4]) =
                    *reinterpret_cast<const float4*>(&sX[c][srow + kh][scol0 + 4]);
                #pragma unroll
                for (int kw = 0; kw < 3; ++kw) {
                    const int kidx = c * 9 + kh * 3 + kw;
                    float wv[8];
                    *reinterpret_cast<float4*>(&wv[0]) =
                        *reinterpret_cast<const float4*>(&sW[kidx][tco * 8]);
                    *reinterpret_cast<float4*>(&wv[4]) =
                        *reinterpret_cast<const float4*>(&sW[kidx][tco * 8 + 4]);
                    #pragma unroll
                    for (int r = 0; r < 8; ++r)
                        #pragma unroll
                        for (int j = 0; j < 4; ++j)
                            acc[r][j] = fmaf(wv[r], xw[kw + j], acc[r][j]);
                }
            }
        }
    }
    const int h = h0 + srow, wc2 = w0 + scol0;
    #pragma unroll
    for (int r = 0; r < 8; ++r) {
        const int co = co0 + tco * 8 + r;
        const float bv = bias[co];
        float4 o;
        o.x = acc[r][0] + bv; o.y = acc[r][1] + bv;
        o.z = acc[r][2] + bv; o.w = acc[r][3] + bv;
        *reinterpret_cast<float4*>(
            &y[(((size_t)n * COUT + co) * HH + h) * WW + wc2]) = o;
    }
}

extern "C" void kernel_launch(void* const* d_in, const int* in_sizes, int n_in,
                              void* d_out, int out_size, void* d_ws, size_t ws_size,
                              hipStream_t stream) {
    const float* x    = (const float*)d_in[0];
    const float* wgt  = (const float*)d_in[1];
    const float* bias = (const float*)d_in[2];
    float* y          = (float*)d_out;

    if (ws_size < WS_NEED) {
        conv3x3_f32<<<2 * 49 * NB, 256, 0, stream>>>(x, wgt, bias, y);
        return;
    }

    u16* xs_hi = (u16*)d_ws;
    u16* xs_lo = xs_hi + XS_ELEMS;
    u16* wp_hi = (u16*)((char*)d_ws + 2*XS_BYTES);
    u16* wp_lo = wp_hi + WP_ELEMS;

    halo_zero<<<(int)((32u*228u*32u + 255u)/256u), 256, 0, stream>>>(xs_hi, xs_lo);
    xsplit<<<32*8*56, 256, 0, stream>>>(x, xs_hi, xs_lo);
    wsplit<<<(int)((WP_ELEMS + 255)/256), 256, 0, stream>>>(wgt, wp_hi, wp_lo);
    conv_mfma<<<2*49*16, 256, 0, stream>>>(xs_hi, xs_lo, wp_hi, wp_lo, bias, y);
}

// Round 6
// 441.480 us; speedup vs baseline: 1.0635x; 1.0635x over previous
//
#include <hip/hip_runtime.h>
#include <hip/hip_bf16.h>

// Conv2d 3x3 s1 p1, NCHW fp32: N=32, Cin=256, H=W=56, Cout=256.
// R6: bf16 hi/lo split, MFMA 32x32x16 (layout HW-verified by R5 pass).
// - Weights packed FRAGMENT-MAJOR in d_ws: every A-fragment ds_read is
//   lane-linear (base + lane*16B) + imm offset -> zero bank conflicts, zero VALU.
// - sX: hi/lo merged into 128B rows (8 slots), slot ^= (cell&7) XOR swizzle
//   (true T2 regime; source-swizzled staging per rule #21).
// - R3's serial stage->sync->compute schedule @ 41.6KB LDS = 3 blocks/CU.

#define NB   32
#define CIN  256
#define HH   56
#define WW   56
#define COUT 256

typedef unsigned short u16;
typedef __attribute__((ext_vector_type(8)))  short bf16x8;
typedef __attribute__((ext_vector_type(16))) float f32x16;

#define XS_ELEMS  (32u*58u*58u*256u)
#define XS_BYTES  ((size_t)XS_ELEMS*2u)
#define WPF_ELEMS (72u*4u*4096u)             // [ck9t][cog4][hl2][m2][ks2][lane64][8]
#define WPF_BYTES ((size_t)WPF_ELEMS*2u)
#define WS_NEED   (2u*XS_BYTES + WPF_BYTES)

__device__ __forceinline__ void gld16(const u16* g, u16* l) {
    __builtin_amdgcn_global_load_lds(
        (const __attribute__((address_space(1))) void*)g,
        (__attribute__((address_space(3))) void*)l, 16, 0, 0);
}

__device__ __forceinline__ u16 bf16_hi_bits(float v, float* hv) {
    __hip_bfloat16 hb = __float2bfloat16(v);
    *hv = __bfloat162float(hb);
    return *reinterpret_cast<u16*>(&hb);
}

// ---- pre-pass 0: zero halo border cells of xs_hi/xs_lo (256 u16 = 32 x 16B) ----
__global__ __launch_bounds__(256) void halo_zero(u16* __restrict__ xh,
                                                 u16* __restrict__ xl) {
    unsigned i = blockIdx.x*256u + threadIdx.x;   // img*228*32 + cell*32 + g
    if (i >= 32u*228u*32u) return;
    unsigned g    = i & 31u;
    unsigned cell = (i >> 5) % 228u;
    unsigned img  = i / (228u*32u);
    unsigned h, w;
    if      (cell < 58)  { h = 0;                w = cell; }
    else if (cell < 116) { h = 57;               w = cell - 58; }
    else if (cell < 172) { h = 1 + (cell - 116); w = 0; }
    else                 { h = 1 + (cell - 172); w = 57; }
    unsigned o = ((img*58u + h)*58u + w)*256u + g*8u;
    uint4 z = {0u,0u,0u,0u};
    *reinterpret_cast<uint4*>(&xh[o]) = z;
    *reinterpret_cast<uint4*>(&xl[o]) = z;
}

// ---- pre-pass 1: x (NCHW f32) -> xs_hi/xs_lo (padded NHWC bf16) ----
__global__ __launch_bounds__(256) void xsplit(const float* __restrict__ x,
                                              u16* __restrict__ xh,
                                              u16* __restrict__ xl) {
    __shared__ float tile[32][57];
    const int t  = threadIdx.x;
    const int b  = blockIdx.x;              // n*(8*56) + cg*56 + h
    const int n  = b / (8*56);
    const int cg = (b / 56) % 8;
    const int h  = b % 56;
    const float* src = x + ((size_t)n*CIN + cg*32) * 3136 + (unsigned)h*56;
    #pragma unroll
    for (int k = 0; k < 7; ++k) {           // 32*56 = 1792 = 7*256
        int idx = t + k*256;
        int c = idx / 56, w = idx % 56;
        tile[c][w] = src[(unsigned)c*3136 + w];
    }
    __syncthreads();
    const unsigned obase = (((unsigned)n*58 + h + 1)*58 + 1)*256 + cg*32;
    #pragma unroll
    for (int k = 0; k < 7; ++k) {
        int idx = t + k*256;
        int w = idx / 32, c = idx % 32;
        float v = tile[c][w];
        float hv;
        u16 hbits = bf16_hi_bits(v, &hv);
        float r;
        u16 lbits = bf16_hi_bits(v - hv, &r);
        unsigned o = obase + (unsigned)w*256 + c;
        xh[o] = hbits;
        xl[o] = lbits;
    }
}

// ---- pre-pass 2: w (OIHW f32) -> wpf, fragment-major ----
// wpf[(ck*9+tap)*4 + cog][hl][m][ks][lane][8]:
//   co = cog*64 + m*32 + (lane&31); ci = ck*32 + ks*16 + (lane>>5)*8 + j
__global__ __launch_bounds__(256) void wsplit(const float* __restrict__ w,
                                              u16* __restrict__ wpf) {
    unsigned i = blockIdx.x*256u + threadIdx.x;   // [chunk288][r2048]
    if (i >= 72u*4u*2048u) return;
    unsigned chunk = i >> 11;                     // (ck*9+tap)*4 + cog
    unsigned r     = i & 2047u;                   // [m][ks][lane][8]
    unsigned cog   = chunk & 3u;
    unsigned ck9t  = chunk >> 2;
    unsigned tap   = ck9t % 9u;
    unsigned ck    = ck9t / 9u;
    unsigned m     = r >> 10;
    unsigned ks    = (r >> 9) & 1u;
    unsigned lane  = (r >> 3) & 63u;
    unsigned j     = r & 7u;
    unsigned co    = cog*64u + m*32u + (lane & 31u);
    unsigned ci    = ck*32u + ks*16u + (lane >> 5)*8u + j;
    float v = w[(size_t)co*2304u + ci*9u + tap];
    float hv;
    u16 hbits = bf16_hi_bits(v, &hv);
    float rr;
    u16 lbits = bf16_hi_bits(v - hv, &rr);
    unsigned base = chunk*4096u;
    wpf[base + r]         = hbits;   // hl = 0
    wpf[base + 2048u + r] = lbits;   // hl = 1
}

// ---- main conv kernel ----
// Block: 256 thr / 4 waves; tile 128co x 2img x (8x8 sp). Wave: 64co x 64sp.
// MFMA 32x32x16 (R5-verified): A row=lane&31, k=(lane>>5)*8+j; B col=lane&31.
// C/D: col=lane&31, row=(reg&3)+8*(reg>>2)+4*(lane>>5).
// sWf: fragment-major [wcb][hl][m][ks][lane][8] -> lane-linear reads, imm offsets.
// sXc: [cell200][slot8][8], slot_phys = slot_logical ^ (cell&7); 128B rows.
__global__ __launch_bounds__(256, 3) void conv_mfma(
    const u16* __restrict__ xs_hi, const u16* __restrict__ xs_lo,
    const u16* __restrict__ wpf,
    const float* __restrict__ bias, float* __restrict__ y) {
    __shared__ __align__(16) u16 sWf[8192];    // 16 KB
    __shared__ __align__(16) u16 sXc[12800];   // 25.6 KB

    const int t    = threadIdx.x;
    const int lane = t & 63, wid = t >> 6;
    const int wc   = wid >> 1;          // co half (0/1)
    const int iwv  = wid & 1;           // image   (0/1)
    const int s5   = lane & 31;
    const int khi  = lane >> 5;

    const int bid  = blockIdx.x;        // (co_t*49 + sp)*16 + nt
    const int co_t = bid / (49*16);
    const int rem  = bid % (49*16);
    const int sp   = rem / 16;
    const int nt   = rem % 16;
    const int h0   = (sp / 7) * 8, w0 = (sp % 7) * 8;
    const int co0  = co_t * 128;
    const int n0   = nt * 2;

    f32x16 acc[2][2];
    #pragma unroll
    for (int m = 0; m < 2; ++m)
        #pragma unroll
        for (int j = 0; j < 2; ++j)
            #pragma unroll
            for (int e = 0; e < 16; ++e) acc[m][j][e] = 0.f;

    auto STAGE_W = [&](int ck, int tap) {
        const unsigned base = ((unsigned)(ck*9 + tap)*4u + (unsigned)co_t*2u)*4096u;
        #pragma unroll
        for (int k = 0; k < 4; ++k) {
            const int s = t + k*256;           // 0..1023 covers both wcb halves
            gld16(wpf + base + (unsigned)s*8u, &sWf[(unsigned)s*8u]);
        }
    };
    auto STAGE_X = [&](int ck) {
        #pragma unroll
        for (int k = 0; k < 7; ++k) {
            const int q = t + k*256;           // 0..1599
            if (q < 1600) {
                const int cell  = q >> 3, sp_  = q & 7;
                const int slog  = sp_ ^ (cell & 7);
                const int hl    = slog >> 2, g = slog & 3;
                const int im    = cell / 100, r100 = cell % 100;
                const int r     = r100 / 10,  c    = r100 % 10;
                const unsigned go = (((unsigned)(n0+im)*58u + (unsigned)(h0+r))*58u
                                     + (unsigned)(w0+c))*256u
                                    + (unsigned)ck*32u + (unsigned)g*8u;
                const u16* src = hl ? xs_lo : xs_hi;
                gld16(src + go, &sXc[(unsigned)q*8u]);
            }
        }
    };

    STAGE_X(0);
    for (int ck = 0; ck < 8; ++ck) {
        for (int tap = 0; tap < 9; ++tap) {
            __syncthreads();                   // overwrite-protect sWf
            STAGE_W(ck, tap);
            __syncthreads();                   // staging complete (vmcnt drained)

            const int kh = tap / 3, kw = tap % 3;
            const u16* wbase = &sWf[((unsigned)wc*512u + (unsigned)lane)*8u];
            int cell[2];
            #pragma unroll
            for (int j = 0; j < 2; ++j)
                cell[j] = iwv*100 + (j*4 + (s5 >> 3) + kh)*10 + (s5 & 7) + kw;

            #pragma unroll
            for (int ks = 0; ks < 2; ++ks) {
                bf16x8 ah[2], al[2], bh[2], bl[2];
                #pragma unroll
                for (int m = 0; m < 2; ++m) {
                    ah[m] = *reinterpret_cast<const bf16x8*>(
                        wbase + (unsigned)((m*128 + ks*64)*8));
                    al[m] = *reinterpret_cast<const bf16x8*>(
                        wbase + (unsigned)((2048 + m*1024 + ks*512)));
                }
                #pragma unroll
                for (int j = 0; j < 2; ++j) {
                    const int c7 = cell[j] & 7;
                    const unsigned rowb = (unsigned)cell[j]*64u;
                    bh[j] = *reinterpret_cast<const bf16x8*>(
                        &sXc[rowb + (unsigned)((ks*2 + khi) ^ c7)*8u]);
                    bl[j] = *reinterpret_cast<const bf16x8*>(
                        &sXc[rowb + (unsigned)((ks*2 + khi + 4) ^ c7)*8u]);
                }
                #pragma unroll
                for (int m = 0; m < 2; ++m)
                    #pragma unroll
                    for (int j = 0; j < 2; ++j) {
                        acc[m][j] = __builtin_amdgcn_mfma_f32_32x32x16_bf16(ah[m], bh[j], acc[m][j], 0, 0, 0);
                        acc[m][j] = __builtin_amdgcn_mfma_f32_32x32x16_bf16(ah[m], bl[j], acc[m][j], 0, 0, 0);
                        acc[m][j] = __builtin_amdgcn_mfma_f32_32x32x16_bf16(al[m], bh[j], acc[m][j], 0, 0, 0);
                    }
            }
        }
        if (ck < 7) {
            __syncthreads();                   // sX reads done; safe to overwrite
            STAGE_X(ck + 1);                   // completes at next tap's barrier
        }
    }

    // ---- epilogue (R5-verified): col=lane&31 (spatial), row=(reg&3)+8*(reg>>2)+4*khi ----
    const int n_img = n0 + iwv;
    #pragma unroll
    for (int m = 0; m < 2; ++m) {
        #pragma unroll
        for (int q = 0; q < 4; ++q) {
            const int cob = co0 + wc*64 + m*32 + 8*q + 4*khi;
            const float4 bv = *reinterpret_cast<const float4*>(&bias[cob]);
            const float bvv[4] = {bv.x, bv.y, bv.z, bv.w};
            #pragma unroll
            for (int j = 0; j < 2; ++j) {
                const int pr = j*4 + (s5 >> 3), pc = s5 & 7;
                #pragma unroll
                for (int rr = 0; rr < 4; ++rr) {
                    const int reg = q*4 + rr;
                    const unsigned yo =
                        (((unsigned)(n_img*COUT + cob + rr))*56u + (unsigned)(h0+pr))*56u
                        + (unsigned)(w0+pc);
                    y[yo] = acc[m][j][reg] + bvv[rr];
                }
            }
        }
    }
}

// ---- fp32 fallback if ws_size is insufficient ----
#define BM 128
#define KC 8
__global__ __launch_bounds__(256, 3) void conv3x3_f32(
    const float* __restrict__ x, const float* __restrict__ wgt,
    const float* __restrict__ bias, float* __restrict__ y) {
    __shared__ float sW[KC * 9][BM];
    __shared__ float sX[KC][10][12];
    const int t = threadIdx.x;
    const int tco = t >> 4, tsp = t & 15;
    const int srow = tsp >> 1, scol0 = (tsp & 1) * 4;
    const int bid = blockIdx.x;
    const int co_t = bid / (49 * NB);
    const int rem = bid % (49 * NB);
    const int sp_t = rem / NB, n = rem % NB;
    const int h0 = (sp_t / 7) * 8, w0 = (sp_t % 7) * 8;
    const int co0 = co_t * BM;
    float acc[8][4];
    #pragma unroll
    for (int r = 0; r < 8; ++r)
        #pragma unroll
        for (int j = 0; j < 4; ++j) acc[r][j] = 0.f;
    const int co_l = t >> 1, half = t & 1;
    for (int ci0 = 0; ci0 < CIN; ci0 += KC) {
        __syncthreads();
        {
            const float4* wsrc = reinterpret_cast<const float4*>(
                wgt + (size_t)(co0 + co_l) * (CIN * 9) + ci0 * 9 + half * 36);
            #pragma unroll
            for (int q = 0; q < 9; ++q) {
                float4 v = wsrc[q];
                const int k0 = half * 36 + q * 4;
                sW[k0 + 0][co_l] = v.x; sW[k0 + 1][co_l] = v.y;
                sW[k0 + 2][co_l] = v.z; sW[k0 + 3][co_l] = v.w;
            }
        }
        for (int idx = t; idx < KC * 100; idx += 256) {
            const int c = idx / 100, r = (idx % 100) / 10, cc = idx % 10;
            const int hh = h0 + r - 1, ww = w0 + cc - 1;
            float v = 0.f;
            if (hh >= 0 && hh < HH && ww >= 0 && ww < WW)
                v = x[(((size_t)n * CIN + (ci0 + c)) * HH + hh) * WW + ww];
            sX[c][r][cc] = v;
        }
        __syncthreads();
        for (int c = 0; c < KC; ++c) {
            #pragma unroll
            for (int kh = 0; kh < 3; ++kh) {
                float xw[8];
                *reinterpret_cast<float4*>(&xw[0]) =
                    *reinterpret_cast<const float4*>(&sX[c][srow + kh][scol0]);
                *reinterpret_cast<float4*>(&xw[4]) =
                    *reinterpret_cast<const float4*>(&sX[c][srow + kh][scol0 + 4]);
                #pragma unroll
                for (int kw = 0; kw < 3; ++kw) {
                    const int kidx = c * 9 + kh * 3 + kw;
                    float wv[8];
                    *reinterpret_cast<float4*>(&wv[0]) =
                        *reinterpret_cast<const float4*>(&sW[kidx][tco * 8]);
                    *reinterpret_cast<float4*>(&wv[4]) =
                        *reinterpret_cast<const float4*>(&sW[kidx][tco * 8 + 4]);
                    #pragma unroll
                    for (int r = 0; r < 8; ++r)
                        #pragma unroll
                        for (int j = 0; j < 4; ++j)
                            acc[r][j] = fmaf(wv[r], xw[kw + j], acc[r][j]);
                }
            }
        }
    }
    const int h = h0 + srow, wc2 = w0 + scol0;
    #pragma unroll
    for (int r = 0; r < 8; ++r) {
        const int co = co0 + tco * 8 + r;
        const float bv = bias[co];
        float4 o;
        o.x = acc[r][0] + bv; o.y = acc[r][1] + bv;
        o.z = acc[r][2] + bv; o.w = acc[r][3] + bv;
        *reinterpret_cast<float4*>(
            &y[(((size_t)n * COUT + co) * HH + h) * WW + wc2]) = o;
    }
}

extern "C" void kernel_launch(void* const* d_in, const int* in_sizes, int n_in,
                              void* d_out, int out_size, void* d_ws, size_t ws_size,
                              hipStream_t stream) {
    const float* x    = (const float*)d_in[0];
    const float* wgt  = (const float*)d_in[1];
    const float* bias = (const float*)d_in[2];
    float* y          = (float*)d_out;

    if (ws_size < WS_NEED) {
        conv3x3_f32<<<2 * 49 * NB, 256, 0, stream>>>(x, wgt, bias, y);
        return;
    }

    u16* xs_hi = (u16*)d_ws;
    u16* xs_lo = xs_hi + XS_ELEMS;
    u16* wpf   = (u16*)((char*)d_ws + 2*XS_BYTES);

    halo_zero<<<(int)((32u*228u*32u + 255u)/256u), 256, 0, stream>>>(xs_hi, xs_lo);
    xsplit<<<32*8*56, 256, 0, stream>>>(x, xs_hi, xs_lo);
    wsplit<<<(int)((72u*4u*2048u + 255u)/256u), 256, 0, stream>>>(wgt, wpf);
    conv_mfma<<<2*49*16, 256, 0, stream>>>(xs_hi, xs_lo, wpf, bias, y);
}